// Round 1
// baseline (253.374 us; speedup 1.0000x reference)
//
#include <hip/hip_runtime.h>
#include <hip/hip_bf16.h>

#define H_IMG 720
#define W_IMG 1280
#define NPIX (H_IMG * W_IMG)
#define NFEAT 8
#define HIDDEN 64
#define DIN 24
#define BLK 128

__device__ __forceinline__ int imin(int a, int b) { return a < b ? a : b; }

__device__ __forceinline__ float fast_tanh(float x) {
  // tanh(x) = (e^{2x}-1)/(e^{2x}+1); clamp to avoid inf/inf
  float cx = fminf(fmaxf(x, -15.f), 15.f);
  float e = __expf(2.f * cx);
  return (e - 1.f) * __builtin_amdgcn_rcpf(e + 1.f);
}

// Trilinear bilateral-grid slice for one view-grid g of shape (8, LG, HG, WG),
// align_corners=True semantics. Writes 8 features (statically indexed).
template <int WG, int HG, int LG>
__device__ __forceinline__ void slice_grid(const float* __restrict__ g,
                                           int row, int col, float gray,
                                           float* __restrict__ out8) {
  const float SX = (float)(WG - 1) / (float)(W_IMG - 1);
  const float SY = (float)(HG - 1) / (float)(H_IMG - 1);
  float x = (float)col * SX;
  float y = (float)row * SY;
  float z = gray * (float)(LG - 1);
  int x0 = (int)x, y0 = (int)y, z0 = (int)z;  // floor (all coords >= 0)
  int x1 = imin(x0 + 1, WG - 1);
  int y1 = imin(y0 + 1, HG - 1);
  int z1 = imin(z0 + 1, LG - 1);
  float wx = x - (float)x0, wy = y - (float)y0, wz = z - (float)z0;
  float ux = 1.f - wx, uy = 1.f - wy, uz = 1.f - wz;

  int i000 = (z0 * HG + y0) * WG + x0;
  int i001 = (z0 * HG + y0) * WG + x1;
  int i010 = (z0 * HG + y1) * WG + x0;
  int i011 = (z0 * HG + y1) * WG + x1;
  int i100 = (z1 * HG + y0) * WG + x0;
  int i101 = (z1 * HG + y0) * WG + x1;
  int i110 = (z1 * HG + y1) * WG + x0;
  int i111 = (z1 * HG + y1) * WG + x1;

  float w000 = uz * uy * ux, w001 = uz * uy * wx;
  float w010 = uz * wy * ux, w011 = uz * wy * wx;
  float w100 = wz * uy * ux, w101 = wz * uy * wx;
  float w110 = wz * wy * ux, w111 = wz * wy * wx;

  const int CS = LG * HG * WG;  // channel stride
#pragma unroll
  for (int c = 0; c < NFEAT; ++c) {
    const float* gc = g + c * CS;
    out8[c] = gc[i000] * w000 + gc[i001] * w001 + gc[i010] * w010 + gc[i011] * w011 +
              gc[i100] * w100 + gc[i101] * w101 + gc[i110] * w110 + gc[i111] * w111;
  }
}

__global__ __launch_bounds__(BLK) void msnbat_kernel(
    const float* __restrict__ rgb,
    const float* __restrict__ g0, const float* __restrict__ g1, const float* __restrict__ g2,
    const float* __restrict__ w1, const float* __restrict__ w2, const float* __restrict__ w3,
    const int* __restrict__ cam, float* __restrict__ out) {
  // Per-thread activation scratch in LDS (rows are thread-private; no barriers).
  // Pad 65: lane l, elem k -> bank (l + k) % 32 -> only free 2-way aliasing.
  __shared__ float act[BLK][HIDDEN + 1];

  const int tid = threadIdx.x;
  const int pix = blockIdx.x * BLK + tid;
  if (pix >= NPIX) return;
  const int row = pix / W_IMG;
  const int col = pix - row * W_IMG;

  const float r = rgb[pix * 3 + 0];
  const float gch = rgb[pix * 3 + 1];
  const float b = rgb[pix * 3 + 2];
  const float gray = fminf(fmaxf(r * 0.299f + gch * 0.587f + b * 0.114f, 0.f), 1.f);

  const int ci = cam[0];

  // ---- slice 3 scales -> 24 features into LDS row ----
  {
    float f8[NFEAT];
    slice_grid<16, 16, 8>(g0 + ci * (NFEAT * 8 * 16 * 16), row, col, gray, f8);
#pragma unroll
    for (int c = 0; c < NFEAT; ++c) act[tid][c] = f8[c];
    slice_grid<12, 12, 8>(g1 + ci * (NFEAT * 8 * 12 * 12), row, col, gray, f8);
#pragma unroll
    for (int c = 0; c < NFEAT; ++c) act[tid][8 + c] = f8[c];
    slice_grid<8, 8, 4>(g2 + ci * (NFEAT * 4 * 8 * 8), row, col, gray, f8);
#pragma unroll
    for (int c = 0; c < NFEAT; ++c) act[tid][16 + c] = f8[c];
  }

  float acc[HIDDEN];

  // ---- layer 1: 24 -> 64 (weights uniform -> s_load; act from LDS) ----
#pragma unroll
  for (int j = 0; j < HIDDEN; ++j) acc[j] = 0.f;
  for (int k = 0; k < DIN; ++k) {
    const float f = act[tid][k];
    const float4* wr = (const float4*)(w1 + (k << 6));
#pragma unroll
    for (int j4 = 0; j4 < HIDDEN / 4; ++j4) {
      float4 wv = wr[j4];
      acc[4 * j4 + 0] = fmaf(f, wv.x, acc[4 * j4 + 0]);
      acc[4 * j4 + 1] = fmaf(f, wv.y, acc[4 * j4 + 1]);
      acc[4 * j4 + 2] = fmaf(f, wv.z, acc[4 * j4 + 2]);
      acc[4 * j4 + 3] = fmaf(f, wv.w, acc[4 * j4 + 3]);
    }
  }
#pragma unroll
  for (int j = 0; j < HIDDEN; ++j) act[tid][j] = fast_tanh(acc[j]);

  // ---- layer 2: 64 -> 64 ----
#pragma unroll
  for (int j = 0; j < HIDDEN; ++j) acc[j] = 0.f;
#pragma unroll 2
  for (int k = 0; k < HIDDEN; ++k) {
    const float hv = act[tid][k];
    const float4* wr = (const float4*)(w2 + (k << 6));
#pragma unroll
    for (int j4 = 0; j4 < HIDDEN / 4; ++j4) {
      float4 wv = wr[j4];
      acc[4 * j4 + 0] = fmaf(hv, wv.x, acc[4 * j4 + 0]);
      acc[4 * j4 + 1] = fmaf(hv, wv.y, acc[4 * j4 + 1]);
      acc[4 * j4 + 2] = fmaf(hv, wv.z, acc[4 * j4 + 2]);
      acc[4 * j4 + 3] = fmaf(hv, wv.w, acc[4 * j4 + 3]);
    }
  }
#pragma unroll
  for (int j = 0; j < HIDDEN; ++j) acc[j] = fast_tanh(acc[j]);

  // ---- layer 3: 64 -> 12 (fully unrolled; acc statically indexed) ----
  float o[12];
#pragma unroll
  for (int j = 0; j < 12; ++j) o[j] = 0.f;
#pragma unroll
  for (int k = 0; k < HIDDEN; ++k) {
    const float hv = acc[k];
#pragma unroll
    for (int j = 0; j < 12; ++j) o[j] = fmaf(hv, w3[k * 12 + j], o[j]);
  }

  // ---- store 12 floats (48 B, 16-B aligned) ----
  float4* op = (float4*)(out + pix * 12);
  op[0] = make_float4(o[0], o[1], o[2], o[3]);
  op[1] = make_float4(o[4], o[5], o[6], o[7]);
  op[2] = make_float4(o[8], o[9], o[10], o[11]);
}

extern "C" void kernel_launch(void* const* d_in, const int* in_sizes, int n_in,
                              void* d_out, int out_size, void* d_ws, size_t ws_size,
                              hipStream_t stream) {
  const float* rgb = (const float*)d_in[0];
  const float* g0 = (const float*)d_in[1];
  const float* g1 = (const float*)d_in[2];
  const float* g2 = (const float*)d_in[3];
  const float* w1 = (const float*)d_in[4];
  const float* w2 = (const float*)d_in[5];
  const float* w3 = (const float*)d_in[6];
  const int* cam = (const int*)d_in[7];
  float* out = (float*)d_out;

  dim3 grid((NPIX + BLK - 1) / BLK), block(BLK);
  hipLaunchKernelGGL(msnbat_kernel, grid, block, 0, stream,
                     rgb, g0, g1, g2, w1, w2, w3, cam, out);
}

// Round 2
// 229.682 us; speedup vs baseline: 1.1032x; 1.1032x over previous
//
#include <hip/hip_runtime.h>
#include <hip/hip_bf16.h>

#define H_IMG 720
#define W_IMG 1280
#define NPIX (H_IMG * W_IMG)
#define NFEAT 8
#define HIDDEN 64
#define DIN 24
#define BLK 256

__device__ __forceinline__ int imin(int a, int b) { return a < b ? a : b; }

__device__ __forceinline__ float fast_tanh(float x) {
  // tanh(x) = (e^{2x}-1)/(e^{2x}+1); clamp to avoid inf/inf
  float cx = fminf(fmaxf(x, -15.f), 15.f);
  float e = __expf(2.f * cx);
  return (e - 1.f) * __builtin_amdgcn_rcpf(e + 1.f);
}

// Trilinear bilateral-grid slice, align_corners=True. g: (8, LG, HG, WG).
template <int WG, int HG, int LG>
__device__ __forceinline__ void slice_grid(const float* __restrict__ g,
                                           int row, int col, float gray,
                                           float* __restrict__ out8) {
  const float SX = (float)(WG - 1) / (float)(W_IMG - 1);
  const float SY = (float)(HG - 1) / (float)(H_IMG - 1);
  float x = (float)col * SX;
  float y = (float)row * SY;
  float z = gray * (float)(LG - 1);
  int x0 = (int)x, y0 = (int)y, z0 = (int)z;  // floor (coords >= 0)
  int x1 = imin(x0 + 1, WG - 1);
  int y1 = imin(y0 + 1, HG - 1);
  int z1 = imin(z0 + 1, LG - 1);
  float wx = x - (float)x0, wy = y - (float)y0, wz = z - (float)z0;
  float ux = 1.f - wx, uy = 1.f - wy, uz = 1.f - wz;

  int i000 = (z0 * HG + y0) * WG + x0;
  int i001 = (z0 * HG + y0) * WG + x1;
  int i010 = (z0 * HG + y1) * WG + x0;
  int i011 = (z0 * HG + y1) * WG + x1;
  int i100 = (z1 * HG + y0) * WG + x0;
  int i101 = (z1 * HG + y0) * WG + x1;
  int i110 = (z1 * HG + y1) * WG + x0;
  int i111 = (z1 * HG + y1) * WG + x1;

  float w000 = uz * uy * ux, w001 = uz * uy * wx;
  float w010 = uz * wy * ux, w011 = uz * wy * wx;
  float w100 = wz * uy * ux, w101 = wz * uy * wx;
  float w110 = wz * wy * ux, w111 = wz * wy * wx;

  const int CS = LG * HG * WG;
#pragma unroll
  for (int c = 0; c < NFEAT; ++c) {
    const float* gc = g + c * CS;
    out8[c] = gc[i000] * w000 + gc[i001] * w001 + gc[i010] * w010 + gc[i011] * w011 +
              gc[i100] * w100 + gc[i101] * w101 + gc[i110] * w110 + gc[i111] * w111;
  }
}

// Prep: transpose w2 (64x64 row-major) -> w2t so column j is a contiguous row.
__global__ __launch_bounds__(256) void transpose_w2_kernel(const float* __restrict__ w2,
                                                           float* __restrict__ w2t) {
  int idx = blockIdx.x * 256 + threadIdx.x;
  if (idx < HIDDEN * HIDDEN) {
    int j = idx >> 6, k = idx & 63;
    w2t[idx] = w2[k * HIDDEN + j];
  }
}

__global__ __launch_bounds__(BLK) void msnbat_kernel(
    const float* __restrict__ rgb,
    const float* __restrict__ g0, const float* __restrict__ g1, const float* __restrict__ g2,
    const float* __restrict__ w1, const float* __restrict__ w2t, const float* __restrict__ w3,
    const int* __restrict__ cam, float* __restrict__ out) {
  const int pix = blockIdx.x * BLK + threadIdx.x;
  if (pix >= NPIX) return;
  const int row = pix / W_IMG;
  const int col = pix - row * W_IMG;

  const float r = rgb[pix * 3 + 0];
  const float gch = rgb[pix * 3 + 1];
  const float b = rgb[pix * 3 + 2];
  const float gray = fminf(fmaxf(r * 0.299f + gch * 0.587f + b * 0.114f, 0.f), 1.f);

  const int ci = cam[0];

  // ---- slice 3 scales -> 24 features, all in registers (static indices) ----
  float f[DIN];
  slice_grid<16, 16, 8>(g0 + ci * (NFEAT * 8 * 16 * 16), row, col, gray, f);
  slice_grid<12, 12, 8>(g1 + ci * (NFEAT * 8 * 12 * 12), row, col, gray, f + 8);
  slice_grid<8, 8, 4>(g2 + ci * (NFEAT * 4 * 8 * 8), row, col, gray, f + 16);

  // ---- layer 1: 24 -> 64, k-outer vector form; weights uniform (s_load) ----
  float h[HIDDEN];
#pragma unroll
  for (int j = 0; j < HIDDEN; ++j) h[j] = 0.f;
#pragma unroll
  for (int k = 0; k < DIN; ++k) {
    const float fv = f[k];
    const float4* wr = (const float4*)(w1 + (k << 6));
#pragma unroll
    for (int j4 = 0; j4 < HIDDEN / 4; ++j4) {
      float4 wv = wr[j4];
      h[4 * j4 + 0] = fmaf(fv, wv.x, h[4 * j4 + 0]);
      h[4 * j4 + 1] = fmaf(fv, wv.y, h[4 * j4 + 1]);
      h[4 * j4 + 2] = fmaf(fv, wv.z, h[4 * j4 + 2]);
      h[4 * j4 + 3] = fmaf(fv, wv.w, h[4 * j4 + 3]);
    }
  }
#pragma unroll
  for (int j = 0; j < HIDDEN; ++j) h[j] = fast_tanh(h[j]);

  // ---- layers 2+3 fused, j-outer: dot(h, w2t row j) -> tanh -> rank-1 into o ----
  float o[12];
#pragma unroll
  for (int i = 0; i < 12; ++i) o[i] = 0.f;
  for (int j = 0; j < HIDDEN; ++j) {  // rolled: uniform j, small code
    const float* wr = w2t + (j << 6);
    float d0 = 0.f, d1 = 0.f, d2 = 0.f, d3 = 0.f;
#pragma unroll
    for (int k = 0; k < HIDDEN; k += 4) {
      d0 = fmaf(h[k + 0], wr[k + 0], d0);
      d1 = fmaf(h[k + 1], wr[k + 1], d1);
      d2 = fmaf(h[k + 2], wr[k + 2], d2);
      d3 = fmaf(h[k + 3], wr[k + 3], d3);
    }
    const float h2 = fast_tanh((d0 + d1) + (d2 + d3));
    const float* w3r = w3 + j * 12;
#pragma unroll
    for (int i = 0; i < 12; ++i) o[i] = fmaf(h2, w3r[i], o[i]);
  }

  // ---- store 12 floats (48 B, 16-B aligned) ----
  float4* op = (float4*)(out + pix * 12);
  op[0] = make_float4(o[0], o[1], o[2], o[3]);
  op[1] = make_float4(o[4], o[5], o[6], o[7]);
  op[2] = make_float4(o[8], o[9], o[10], o[11]);
}

extern "C" void kernel_launch(void* const* d_in, const int* in_sizes, int n_in,
                              void* d_out, int out_size, void* d_ws, size_t ws_size,
                              hipStream_t stream) {
  const float* rgb = (const float*)d_in[0];
  const float* g0 = (const float*)d_in[1];
  const float* g1 = (const float*)d_in[2];
  const float* g2 = (const float*)d_in[3];
  const float* w1 = (const float*)d_in[4];
  const float* w2 = (const float*)d_in[5];
  const float* w3 = (const float*)d_in[6];
  const int* cam = (const int*)d_in[7];
  float* out = (float*)d_out;
  float* w2t = (float*)d_ws;  // 64*64*4 = 16 KB scratch

  hipLaunchKernelGGL(transpose_w2_kernel, dim3((HIDDEN * HIDDEN + 255) / 256), dim3(256),
                     0, stream, w2, w2t);
  hipLaunchKernelGGL(msnbat_kernel, dim3((NPIX + BLK - 1) / BLK), dim3(BLK), 0, stream,
                     rgb, g0, g1, g2, w1, w2t, w3, cam, out);
}

// Round 4
// 80.185 us; speedup vs baseline: 3.1598x; 2.8644x over previous
//
#include <hip/hip_runtime.h>
#include <hip/hip_bf16.h>

#define H_IMG 720
#define W_IMG 1280
#define NPIX (H_IMG * W_IMG)

typedef __attribute__((ext_vector_type(4))) float f32x4;
typedef __attribute__((ext_vector_type(8))) short short8;
typedef __attribute__((ext_vector_type(4))) short short4v;

// ---- workspace layout (bytes) ----
// wpack: 28 frags (14 hi + 14 lo) * 64 lanes * 16B
#define WPACK_BYTES (28 * 64 * 16)
#define GP0_OFF WPACK_BYTES
#define GP0_N (16 * 16 * 8 * 8)   // [y][x][z][c] f32
#define GP1_OFF (GP0_OFF + GP0_N * 4)
#define GP1_N (12 * 12 * 8 * 8)
#define GP2_OFF (GP1_OFF + GP1_N * 4)
#define GP2_N (8 * 8 * 4 * 8)

#define XSTR 36   // ushorts per X row (24 feats + 8 zero-pad + 4 pad)
#define HSTR 76   // ushorts per H row (64 feats + 12 pad) -> 152B stride, ~2-way banks

__device__ __forceinline__ short f2bf(float x) {
  __hip_bfloat16 h = __float2bfloat16(x);
  return *reinterpret_cast<short*>(&h);
}

__device__ __forceinline__ float tanh5(float x) {
  // tanh(x) = 1 - 2/(e^{2x}+1); graceful at +-inf, no clamp needed.
  float e2 = __builtin_amdgcn_exp2f(x * 2.885390081777927f);  // e^{2x} via v_exp_f32
  return fmaf(-2.f, __builtin_amdgcn_rcpf(e2 + 1.f), 1.f);
}

// ================= prep kernel =================
__global__ __launch_bounds__(256) void prep_kernel(
    const float* __restrict__ g0, const float* __restrict__ g1, const float* __restrict__ g2,
    const float* __restrict__ w1, const float* __restrict__ w2, const float* __restrict__ w3,
    const int* __restrict__ cam, void* __restrict__ ws) {
  ushort* wpack = (ushort*)ws;
  float* gp0 = (float*)((char*)ws + GP0_OFF);
  float* gp1 = (float*)((char*)ws + GP1_OFF);
  float* gp2 = (float*)((char*)ws + GP2_OFF);
  const int ci = cam[0];
  const int tid = blockIdx.x * 256 + threadIdx.x;
  const int nth = gridDim.x * 256;

  // grids -> [y][x][z][c] f32, selected view only
  for (int e = tid; e < GP0_N; e += nth) {
    int c = e & 7; int t = e >> 3; int z = t & 7; t >>= 3; int x = t & 15; int y = t >> 4;
    gp0[e] = g0[ci * GP0_N + ((c * 8 + z) * 16 + y) * 16 + x];
  }
  for (int e = tid; e < GP1_N; e += nth) {
    int c = e & 7; int t = e >> 3; int z = t & 7; t >>= 3; int x = t % 12; int y = t / 12;
    gp1[e] = g1[ci * GP1_N + ((c * 8 + z) * 12 + y) * 12 + x];
  }
  for (int e = tid; e < GP2_N; e += nth) {
    int c = e & 7; int t = e >> 3; int z = t & 3; t >>= 2; int x = t & 7; int y = t >> 3;
    gp2[e] = g2[ci * GP2_N + ((c * 4 + z) * 8 + y) * 8 + x];
  }

  // weights -> per-lane A-fragments (A = W^T), hi/lo bf16 split.
  // frag f: 0..3 = L1 (mt), 4..11 = L2 (4+ks*4+mt), 12..13 = L3 (ks). lo at f+14.
  for (int fl = tid; fl < 14 * 64; fl += nth) {
    int f = fl >> 6, lane = fl & 63;
    int g = lane >> 4, r = lane & 15;
    ushort* dh = wpack + fl * 8;
    ushort* dl = wpack + (14 * 64 + fl) * 8;
#pragma unroll
    for (int j = 0; j < 8; ++j) {
      float v = 0.f;
      if (f < 4) {
        int k = 8 * g + j, n = r + 16 * f;
        if (k < 24) v = w1[k * 64 + n];
      } else if (f < 12) {
        int q = f - 4, ks = q >> 2, mt = q & 3;
        v = w2[(8 * g + j + 32 * ks) * 64 + (r + 16 * mt)];
      } else {
        int ks = f - 12;
        if (r < 12) v = w3[(8 * g + j + 32 * ks) * 12 + r];
      }
      __hip_bfloat16 bh = __float2bfloat16(v);
      float vh = __bfloat162float(bh);
      __hip_bfloat16 bl = __float2bfloat16(v - vh);
      dh[j] = *(ushort*)&bh;
      dl[j] = *(ushort*)&bl;
    }
  }
}

// ================= slicing =================
template <int WG, int HG, int LG>
__device__ __forceinline__ void slice_pack(const float* __restrict__ gp,
                                           int row, int col, float gray,
                                           float* __restrict__ out8) {
  float x = (float)col * ((float)(WG - 1) / (float)(W_IMG - 1));
  float y = (float)row * ((float)(HG - 1) / (float)(H_IMG - 1));
  float z = gray * (float)(LG - 1);
  int x0 = (int)x, y0 = (int)y, z0 = (int)z;
  int x1 = min(x0 + 1, WG - 1), y1 = min(y0 + 1, HG - 1), z1 = min(z0 + 1, LG - 1);
  float wx = x - (float)x0, wy = y - (float)y0, wz = z - (float)z0;

  const float* p00 = gp + ((y0 * WG + x0) * LG) * 8;
  const float* p01 = gp + ((y0 * WG + x1) * LG) * 8;
  const float* p10 = gp + ((y1 * WG + x0) * LG) * 8;
  const float* p11 = gp + ((y1 * WG + x1) * LG) * 8;

  // 8 channels per z-slab, 16B-aligned f32x4 pairs
  f32x4 s00a = *(const f32x4*)(p00 + z0 * 8), s00b = *(const f32x4*)(p00 + z0 * 8 + 4);
  f32x4 s01a = *(const f32x4*)(p01 + z0 * 8), s01b = *(const f32x4*)(p01 + z0 * 8 + 4);
  f32x4 s10a = *(const f32x4*)(p10 + z0 * 8), s10b = *(const f32x4*)(p10 + z0 * 8 + 4);
  f32x4 s11a = *(const f32x4*)(p11 + z0 * 8), s11b = *(const f32x4*)(p11 + z0 * 8 + 4);
  f32x4 t00a = *(const f32x4*)(p00 + z1 * 8), t00b = *(const f32x4*)(p00 + z1 * 8 + 4);
  f32x4 t01a = *(const f32x4*)(p01 + z1 * 8), t01b = *(const f32x4*)(p01 + z1 * 8 + 4);
  f32x4 t10a = *(const f32x4*)(p10 + z1 * 8), t10b = *(const f32x4*)(p10 + z1 * 8 + 4);
  f32x4 t11a = *(const f32x4*)(p11 + z1 * 8), t11b = *(const f32x4*)(p11 + z1 * 8 + 4);

#pragma unroll
  for (int c = 0; c < 8; ++c) {
    float c00 = (c < 4) ? s00a[c & 3] : s00b[c & 3];
    float c01 = (c < 4) ? s01a[c & 3] : s01b[c & 3];
    float c10 = (c < 4) ? s10a[c & 3] : s10b[c & 3];
    float c11 = (c < 4) ? s11a[c & 3] : s11b[c & 3];
    float d00 = (c < 4) ? t00a[c & 3] : t00b[c & 3];
    float d01 = (c < 4) ? t01a[c & 3] : t01b[c & 3];
    float d10 = (c < 4) ? t10a[c & 3] : t10b[c & 3];
    float d11 = (c < 4) ? t11a[c & 3] : t11b[c & 3];
    float h0 = fmaf(wx, c01 - c00, c00);
    float h1 = fmaf(wx, c11 - c10, c10);
    float v0 = fmaf(wy, h1 - h0, h0);
    float g0v = fmaf(wx, d01 - d00, d00);
    float g1v = fmaf(wx, d11 - d10, d10);
    float v1 = fmaf(wy, g1v - g0v, g0v);
    out8[c] = fmaf(wz, v1 - v0, v0);
  }
}

// ================= main kernel =================
__global__ __launch_bounds__(256) void msnbat_kernel(
    const float* __restrict__ rgb, const void* __restrict__ ws, float* __restrict__ out) {
  __shared__ ushort LDS[4][64 * HSTR];  // 38912 B; per-wave private regions, no barriers

  const ushort* wpack = (const ushort*)ws;
  const short8* wp = (const short8*)wpack;  // frag f, lane l -> wp[f*64+l]
  const float* gp0 = (const float*)((const char*)ws + GP0_OFF);
  const float* gp1 = (const float*)((const char*)ws + GP1_OFF);
  const float* gp2 = (const float*)((const char*)ws + GP2_OFF);

  const int wave = threadIdx.x >> 6, lane = threadIdx.x & 63;
  const int g = lane >> 4, r = lane & 15;
  ushort* W = LDS[wave];
  const int pixbase = blockIdx.x * 256 + wave * 64;
  const int p = pixbase + lane;
  const int row = p / W_IMG;
  const int col = p - row * W_IMG;

  const float rr = rgb[p * 3 + 0], gg = rgb[p * 3 + 1], bb = rgb[p * 3 + 2];
  const float gray = fminf(fmaxf(rr * 0.299f + gg * 0.587f + bb * 0.114f, 0.f), 1.f);

  // ---- slice 24 features (lane = its own pixel) ----
  float f[24];
  slice_pack<16, 16, 8>(gp0, row, col, gray, f);
  slice_pack<12, 12, 8>(gp1, row, col, gray, f + 8);
  slice_pack<8, 8, 4>(gp2, row, col, gray, f + 16);

  // ---- stage X^T in LDS as bf16: row = pixel(lane), feats 0..23, 24..31 zeroed ----
#pragma unroll
  for (int w4 = 0; w4 < 6; ++w4) {
    short4v v = {f2bf(f[w4 * 4 + 0]), f2bf(f[w4 * 4 + 1]), f2bf(f[w4 * 4 + 2]), f2bf(f[w4 * 4 + 3])};
    *(short4v*)&W[lane * XSTR + w4 * 4] = v;
  }
  {
    short4v z4 = {0, 0, 0, 0};
    *(short4v*)&W[lane * XSTR + 24] = z4;
    *(short4v*)&W[lane * XSTR + 28] = z4;
  }

  // ---- B1 frags: lane(g,r) reads X[pixel r+16nt][feat 8g+j] ----
  short8 B1[4];
#pragma unroll
  for (int nt = 0; nt < 4; ++nt) {
    short4v lo = *(short4v*)&W[(r + 16 * nt) * XSTR + 8 * g];
    short4v hi = *(short4v*)&W[(r + 16 * nt) * XSTR + 8 * g + 4];
    B1[nt] = __builtin_shufflevector(lo, hi, 0, 1, 2, 3, 4, 5, 6, 7);
  }

  // ---- L1: C = W1^T * X^T  (M=64 feats, N=64 px, K=32) ----
  f32x4 acc[4][4];
#pragma unroll
  for (int mt = 0; mt < 4; ++mt)
#pragma unroll
    for (int nt = 0; nt < 4; ++nt) acc[mt][nt] = (f32x4){0.f, 0.f, 0.f, 0.f};
#pragma unroll
  for (int mt = 0; mt < 4; ++mt) {
    short8 A = wp[mt * 64 + lane];
#pragma unroll
    for (int nt = 0; nt < 4; ++nt)
      acc[mt][nt] = __builtin_amdgcn_mfma_f32_16x16x32_bf16(A, B1[nt], acc[mt][nt], 0, 0, 0);
  }
#pragma unroll
  for (int mt = 0; mt < 4; ++mt) {  // lo pass
    short8 A = wp[(14 + mt) * 64 + lane];
#pragma unroll
    for (int nt = 0; nt < 4; ++nt)
      acc[mt][nt] = __builtin_amdgcn_mfma_f32_16x16x32_bf16(A, B1[nt], acc[mt][nt], 0, 0, 0);
  }

  // ---- tanh -> H1 in LDS (row = pixel 16nt+r, feat = 16mt+4g+d) ----
#pragma unroll
  for (int mt = 0; mt < 4; ++mt)
#pragma unroll
    for (int nt = 0; nt < 4; ++nt) {
      f32x4 v = acc[mt][nt];
      short4v pk = {f2bf(tanh5(v[0])), f2bf(tanh5(v[1])), f2bf(tanh5(v[2])), f2bf(tanh5(v[3]))};
      *(short4v*)&W[(16 * nt + r) * HSTR + 16 * mt + 4 * g] = pk;
    }

  // ---- B2 frags: H1[pixel r+16nt][feat 8g+j+32ks] ----
  short8 B2[4][2];
#pragma unroll
  for (int nt = 0; nt < 4; ++nt)
#pragma unroll
    for (int ks = 0; ks < 2; ++ks) {
      short4v lo = *(short4v*)&W[(16 * nt + r) * HSTR + 32 * ks + 8 * g];
      short4v hi = *(short4v*)&W[(16 * nt + r) * HSTR + 32 * ks + 8 * g + 4];
      B2[nt][ks] = __builtin_shufflevector(lo, hi, 0, 1, 2, 3, 4, 5, 6, 7);
    }

  // ---- L2: K=64 (2 ks), hi + lo passes ----
#pragma unroll
  for (int mt = 0; mt < 4; ++mt)
#pragma unroll
    for (int nt = 0; nt < 4; ++nt) acc[mt][nt] = (f32x4){0.f, 0.f, 0.f, 0.f};
#pragma unroll
  for (int ks = 0; ks < 2; ++ks)
#pragma unroll
    for (int mt = 0; mt < 4; ++mt) {
      short8 A = wp[(4 + ks * 4 + mt) * 64 + lane];
#pragma unroll
      for (int nt = 0; nt < 4; ++nt)
        acc[mt][nt] = __builtin_amdgcn_mfma_f32_16x16x32_bf16(A, B2[nt][ks], acc[mt][nt], 0, 0, 0);
    }
#pragma unroll
  for (int ks = 0; ks < 2; ++ks)
#pragma unroll
    for (int mt = 0; mt < 4; ++mt) {
      short8 A = wp[(18 + ks * 4 + mt) * 64 + lane];
#pragma unroll
      for (int nt = 0; nt < 4; ++nt)
        acc[mt][nt] = __builtin_amdgcn_mfma_f32_16x16x32_bf16(A, B2[nt][ks], acc[mt][nt], 0, 0, 0);
    }

  // ---- tanh -> H2 (same LDS rows; wave-private in-order DS keeps RAW/WAR safe) ----
#pragma unroll
  for (int mt = 0; mt < 4; ++mt)
#pragma unroll
    for (int nt = 0; nt < 4; ++nt) {
      f32x4 v = acc[mt][nt];
      short4v pk = {f2bf(tanh5(v[0])), f2bf(tanh5(v[1])), f2bf(tanh5(v[2])), f2bf(tanh5(v[3]))};
      *(short4v*)&W[(16 * nt + r) * HSTR + 16 * mt + 4 * g] = pk;
    }

  // ---- B3 frags + L3: M=16 (12 valid), N=64 px, K=64 ----
  short8 B3[4][2];
#pragma unroll
  for (int nt = 0; nt < 4; ++nt)
#pragma unroll
    for (int ks = 0; ks < 2; ++ks) {
      short4v lo = *(short4v*)&W[(16 * nt + r) * HSTR + 32 * ks + 8 * g];
      short4v hi = *(short4v*)&W[(16 * nt + r) * HSTR + 32 * ks + 8 * g + 4];
      B3[nt][ks] = __builtin_shufflevector(lo, hi, 0, 1, 2, 3, 4, 5, 6, 7);
    }
  f32x4 acc3[4];
#pragma unroll
  for (int nt = 0; nt < 4; ++nt) acc3[nt] = (f32x4){0.f, 0.f, 0.f, 0.f};
#pragma unroll
  for (int ks = 0; ks < 2; ++ks) {
    short8 A = wp[(12 + ks) * 64 + lane];
#pragma unroll
    for (int nt = 0; nt < 4; ++nt)
      acc3[nt] = __builtin_amdgcn_mfma_f32_16x16x32_bf16(A, B3[nt][ks], acc3[nt], 0, 0, 0);
  }
#pragma unroll
  for (int ks = 0; ks < 2; ++ks) {
    short8 A = wp[(26 + ks) * 64 + lane];
#pragma unroll
    for (int nt = 0; nt < 4; ++nt)
      acc3[nt] = __builtin_amdgcn_mfma_f32_16x16x32_bf16(A, B3[nt][ks], acc3[nt], 0, 0, 0);
  }

  // ---- store: lane(g<3, r) holds channels 4g..4g+3 of pixel 16nt+r -> f32x4 ----
  if (g < 3) {
#pragma unroll
    for (int nt = 0; nt < 4; ++nt) {
      int pix = pixbase + 16 * nt + r;
      *(f32x4*)(out + pix * 12 + 4 * g) = acc3[nt];
    }
  }
}

extern "C" void kernel_launch(void* const* d_in, const int* in_sizes, int n_in,
                              void* d_out, int out_size, void* d_ws, size_t ws_size,
                              hipStream_t stream) {
  const float* rgb = (const float*)d_in[0];
  const float* g0 = (const float*)d_in[1];
  const float* g1 = (const float*)d_in[2];
  const float* g2 = (const float*)d_in[3];
  const float* w1 = (const float*)d_in[4];
  const float* w2 = (const float*)d_in[5];
  const float* w3 = (const float*)d_in[6];
  const int* cam = (const int*)d_in[7];
  float* out = (float*)d_out;

  hipLaunchKernelGGL(prep_kernel, dim3(64), dim3(256), 0, stream,
                     g0, g1, g2, w1, w2, w3, cam, d_ws);
  hipLaunchKernelGGL(msnbat_kernel, dim3(NPIX / 256), dim3(256), 0, stream,
                     rgb, d_ws, out);
}

// Round 5
// 63.734 us; speedup vs baseline: 3.9755x; 1.2581x over previous
//
#include <hip/hip_runtime.h>
#include <hip/hip_bf16.h>

#define H_IMG 720
#define W_IMG 1280
#define NPIX (H_IMG * W_IMG)

typedef __attribute__((ext_vector_type(4))) float f32x4;
typedef __attribute__((ext_vector_type(8))) short short8;
typedef __attribute__((ext_vector_type(4))) short short4v;

// ---- workspace layout (bytes) ----
// wpack: 14 hi-frags * 64 lanes * 16B (lo pass dropped)
#define WPACK_BYTES (14 * 64 * 16)
#define GP0_OFF WPACK_BYTES
#define GP0_N (16 * 16 * 8 * 8)   // [y][x][z][c] f32
#define GP1_OFF (GP0_OFF + GP0_N * 4)
#define GP1_N (12 * 12 * 8 * 8)
#define GP2_OFF (GP1_OFF + GP1_N * 4)
#define GP2_N (8 * 8 * 4 * 8)

#define XSTR 36  // ushorts per staging row: 32 payload + 4 pad (18 dwords -> optimal banks)

__device__ __forceinline__ uint pkbf(float a, float b) {
  // packed f32x2 -> bf16x2 (v_cvt_pk_bf16_f32), RNE
  float2 t2 = make_float2(a, b);
  __hip_bfloat162 t = __float22bfloat162_rn(t2);
  uint u;
  __builtin_memcpy(&u, &t, 4);
  return u;
}

__device__ __forceinline__ float tanh5(float x) {
  // tanh(x) = 1 - 2/(e^{2x}+1); graceful at +-inf, no clamp needed.
  float e2 = __builtin_amdgcn_exp2f(x * 2.885390081777927f);  // e^{2x} via v_exp_f32
  return fmaf(-2.f, __builtin_amdgcn_rcpf(e2 + 1.f), 1.f);
}

// ================= prep kernel =================
__global__ __launch_bounds__(256) void prep_kernel(
    const float* __restrict__ g0, const float* __restrict__ g1, const float* __restrict__ g2,
    const float* __restrict__ w1, const float* __restrict__ w2, const float* __restrict__ w3,
    const int* __restrict__ cam, void* __restrict__ ws) {
  ushort* wpack = (ushort*)ws;
  float* gp0 = (float*)((char*)ws + GP0_OFF);
  float* gp1 = (float*)((char*)ws + GP1_OFF);
  float* gp2 = (float*)((char*)ws + GP2_OFF);
  const int ci = cam[0];
  const int tid = blockIdx.x * 256 + threadIdx.x;
  const int nth = gridDim.x * 256;

  // grids -> [y][x][z][c] f32, selected view only
  for (int e = tid; e < GP0_N; e += nth) {
    int c = e & 7; int t = e >> 3; int z = t & 7; t >>= 3; int x = t & 15; int y = t >> 4;
    gp0[e] = g0[ci * GP0_N + ((c * 8 + z) * 16 + y) * 16 + x];
  }
  for (int e = tid; e < GP1_N; e += nth) {
    int c = e & 7; int t = e >> 3; int z = t & 7; t >>= 3; int x = t % 12; int y = t / 12;
    gp1[e] = g1[ci * GP1_N + ((c * 8 + z) * 12 + y) * 12 + x];
  }
  for (int e = tid; e < GP2_N; e += nth) {
    int c = e & 7; int t = e >> 3; int z = t & 3; t >>= 2; int x = t & 7; int y = t >> 3;
    gp2[e] = g2[ci * GP2_N + ((c * 4 + z) * 8 + y) * 8 + x];
  }

  // weights -> per-lane A-fragments (A = W^T), hi bf16 only.
  // frag f: 0..3 = L1 (mt), 4..11 = L2 (4+ks*4+mt), 12..13 = L3 (ks).
  for (int fl = tid; fl < 14 * 64; fl += nth) {
    int f = fl >> 6, lane = fl & 63;
    int g = lane >> 4, r = lane & 15;
    ushort* dh = wpack + fl * 8;
#pragma unroll
    for (int j = 0; j < 8; ++j) {
      float v = 0.f;
      if (f < 4) {
        int k = 8 * g + j, n = r + 16 * f;
        if (k < 24) v = w1[k * 64 + n];
      } else if (f < 12) {
        int q = f - 4, ks = q >> 2, mt = q & 3;
        v = w2[(8 * g + j + 32 * ks) * 64 + (r + 16 * mt)];
      } else {
        int ks = f - 12;
        if (r < 12) v = w3[(8 * g + j + 32 * ks) * 12 + r];
      }
      __hip_bfloat16 bh = __float2bfloat16(v);
      dh[j] = *(ushort*)&bh;
    }
  }
}

// ================= slicing =================
template <int WG, int HG, int LG>
__device__ __forceinline__ void slice_pack(const float* __restrict__ gp,
                                           int row, int col, float gray,
                                           float* __restrict__ out8) {
  float x = (float)col * ((float)(WG - 1) / (float)(W_IMG - 1));
  float y = (float)row * ((float)(HG - 1) / (float)(H_IMG - 1));
  float z = gray * (float)(LG - 1);
  int x0 = (int)x, y0 = (int)y, z0 = (int)z;
  int x1 = min(x0 + 1, WG - 1), y1 = min(y0 + 1, HG - 1), z1 = min(z0 + 1, LG - 1);
  float wx = x - (float)x0, wy = y - (float)y0, wz = z - (float)z0;

  const float* p00 = gp + ((y0 * WG + x0) * LG) * 8;
  const float* p01 = gp + ((y0 * WG + x1) * LG) * 8;
  const float* p10 = gp + ((y1 * WG + x0) * LG) * 8;
  const float* p11 = gp + ((y1 * WG + x1) * LG) * 8;

  f32x4 s00a = *(const f32x4*)(p00 + z0 * 8), s00b = *(const f32x4*)(p00 + z0 * 8 + 4);
  f32x4 s01a = *(const f32x4*)(p01 + z0 * 8), s01b = *(const f32x4*)(p01 + z0 * 8 + 4);
  f32x4 s10a = *(const f32x4*)(p10 + z0 * 8), s10b = *(const f32x4*)(p10 + z0 * 8 + 4);
  f32x4 s11a = *(const f32x4*)(p11 + z0 * 8), s11b = *(const f32x4*)(p11 + z0 * 8 + 4);
  f32x4 t00a = *(const f32x4*)(p00 + z1 * 8), t00b = *(const f32x4*)(p00 + z1 * 8 + 4);
  f32x4 t01a = *(const f32x4*)(p01 + z1 * 8), t01b = *(const f32x4*)(p01 + z1 * 8 + 4);
  f32x4 t10a = *(const f32x4*)(p10 + z1 * 8), t10b = *(const f32x4*)(p10 + z1 * 8 + 4);
  f32x4 t11a = *(const f32x4*)(p11 + z1 * 8), t11b = *(const f32x4*)(p11 + z1 * 8 + 4);

#pragma unroll
  for (int c = 0; c < 8; ++c) {
    float c00 = (c < 4) ? s00a[c & 3] : s00b[c & 3];
    float c01 = (c < 4) ? s01a[c & 3] : s01b[c & 3];
    float c10 = (c < 4) ? s10a[c & 3] : s10b[c & 3];
    float c11 = (c < 4) ? s11a[c & 3] : s11b[c & 3];
    float d00 = (c < 4) ? t00a[c & 3] : t00b[c & 3];
    float d01 = (c < 4) ? t01a[c & 3] : t01b[c & 3];
    float d10 = (c < 4) ? t10a[c & 3] : t10b[c & 3];
    float d11 = (c < 4) ? t11a[c & 3] : t11b[c & 3];
    float h0 = fmaf(wx, c01 - c00, c00);
    float h1 = fmaf(wx, c11 - c10, c10);
    float v0 = fmaf(wy, h1 - h0, h0);
    float g0v = fmaf(wx, d01 - d00, d00);
    float g1v = fmaf(wx, d11 - d10, d10);
    float v1 = fmaf(wy, g1v - g0v, g0v);
    out8[c] = fmaf(wz, v1 - v0, v0);
  }
}

// ================= main kernel =================
// One reused 64x36-ushort staging region per wave: X -> H1a -> H1b -> H2a -> H2b.
// All DS traffic is wave-private and in-order; no barriers anywhere.
__global__ __launch_bounds__(256, 5) void msnbat_kernel(
    const float* __restrict__ rgb, const void* __restrict__ ws, float* __restrict__ out) {
  __shared__ ushort LDS[4][64 * XSTR];  // 18432 B/block

  const short8* wp = (const short8*)ws;  // frag f, lane l -> wp[f*64+l]
  const float* gp0 = (const float*)((const char*)ws + GP0_OFF);
  const float* gp1 = (const float*)((const char*)ws + GP1_OFF);
  const float* gp2 = (const float*)((const char*)ws + GP2_OFF);

  const int wave = threadIdx.x >> 6, lane = threadIdx.x & 63;
  const int g = lane >> 4, r = lane & 15;
  ushort* W = LDS[wave];
  uint* Wu = (uint*)W;
  const int pixbase = blockIdx.x * 256 + wave * 64;
  const int p = pixbase + lane;
  const int row = p / W_IMG;
  const int col = p - row * W_IMG;

  const float rr = rgb[p * 3 + 0], gg = rgb[p * 3 + 1], bb = rgb[p * 3 + 2];
  const float gray = fminf(fmaxf(rr * 0.299f + gg * 0.587f + bb * 0.114f, 0.f), 1.f);

  // ---- slice 24 features (lane = its own pixel) ----
  float f[24];
  slice_pack<16, 16, 8>(gp0, row, col, gray, f);
  slice_pack<12, 12, 8>(gp1, row, col, gray, f + 8);
  slice_pack<8, 8, 4>(gp2, row, col, gray, f + 16);

  // ---- stage X: row = pixel(lane), cols 0..23 bf16 feats, 24..31 zero ----
  {
    const int ub = lane * 18;  // uint base of this row
#pragma unroll
    for (int i = 0; i < 6; ++i) {
      uint2 v = make_uint2(pkbf(f[4 * i + 0], f[4 * i + 1]), pkbf(f[4 * i + 2], f[4 * i + 3]));
      *(uint2*)&Wu[ub + 2 * i] = v;
    }
    uint2 z2 = make_uint2(0u, 0u);
    *(uint2*)&Wu[ub + 12] = z2;
    *(uint2*)&Wu[ub + 14] = z2;
  }

  // ---- B1 frags: lane(g,r) reads X[pixel r+16nt][feat 8g+j] ----
  short8 B1[4];
#pragma unroll
  for (int nt = 0; nt < 4; ++nt) {
    short4v lo = *(short4v*)&W[(r + 16 * nt) * XSTR + 8 * g];
    short4v hi = *(short4v*)&W[(r + 16 * nt) * XSTR + 8 * g + 4];
    B1[nt] = __builtin_shufflevector(lo, hi, 0, 1, 2, 3, 4, 5, 6, 7);
  }

  // ---- L1 (24->64) in mt-halves; stage tanh(H1) halves; build B2 frags ----
  short8 B2[2][4];
#pragma unroll
  for (int half = 0; half < 2; ++half) {
#pragma unroll
    for (int mtl = 0; mtl < 2; ++mtl) {
      const int mt = 2 * half + mtl;
      short8 A = wp[mt * 64 + lane];
      f32x4 a[4];
#pragma unroll
      for (int nt = 0; nt < 4; ++nt) a[nt] = (f32x4){0.f, 0.f, 0.f, 0.f};
#pragma unroll
      for (int nt = 0; nt < 4; ++nt)
        a[nt] = __builtin_amdgcn_mfma_f32_16x16x32_bf16(A, B1[nt], a[nt], 0, 0, 0);
#pragma unroll
      for (int nt = 0; nt < 4; ++nt) {
        uint2 v = make_uint2(pkbf(tanh5(a[nt][0]), tanh5(a[nt][1])),
                             pkbf(tanh5(a[nt][2]), tanh5(a[nt][3])));
        *(uint2*)&Wu[(16 * nt + r) * 18 + 8 * mtl + 2 * g] = v;
      }
    }
#pragma unroll
    for (int nt = 0; nt < 4; ++nt) {
      short4v lo = *(short4v*)&W[(16 * nt + r) * XSTR + 8 * g];
      short4v hi = *(short4v*)&W[(16 * nt + r) * XSTR + 8 * g + 4];
      B2[half][nt] = __builtin_shufflevector(lo, hi, 0, 1, 2, 3, 4, 5, 6, 7);
    }
  }

  // ---- L2 (64->64) in mt-halves; stage tanh(H2) halves; build B3 frags ----
  short8 B3[2][4];
#pragma unroll
  for (int half = 0; half < 2; ++half) {
#pragma unroll
    for (int mtl = 0; mtl < 2; ++mtl) {
      const int mt = 2 * half + mtl;
      short8 A0 = wp[(4 + mt) * 64 + lane];  // ks=0
      short8 A1 = wp[(8 + mt) * 64 + lane];  // ks=1
      f32x4 a[4];
#pragma unroll
      for (int nt = 0; nt < 4; ++nt) a[nt] = (f32x4){0.f, 0.f, 0.f, 0.f};
#pragma unroll
      for (int nt = 0; nt < 4; ++nt)
        a[nt] = __builtin_amdgcn_mfma_f32_16x16x32_bf16(A0, B2[0][nt], a[nt], 0, 0, 0);
#pragma unroll
      for (int nt = 0; nt < 4; ++nt)
        a[nt] = __builtin_amdgcn_mfma_f32_16x16x32_bf16(A1, B2[1][nt], a[nt], 0, 0, 0);
#pragma unroll
      for (int nt = 0; nt < 4; ++nt) {
        uint2 v = make_uint2(pkbf(tanh5(a[nt][0]), tanh5(a[nt][1])),
                             pkbf(tanh5(a[nt][2]), tanh5(a[nt][3])));
        *(uint2*)&Wu[(16 * nt + r) * 18 + 8 * mtl + 2 * g] = v;
      }
    }
#pragma unroll
    for (int nt = 0; nt < 4; ++nt) {
      short4v lo = *(short4v*)&W[(16 * nt + r) * XSTR + 8 * g];
      short4v hi = *(short4v*)&W[(16 * nt + r) * XSTR + 8 * g + 4];
      B3[half][nt] = __builtin_shufflevector(lo, hi, 0, 1, 2, 3, 4, 5, 6, 7);
    }
  }

  // ---- L3 (64->12): M=16 (12 valid), K=64 ----
  f32x4 acc3[4];
#pragma unroll
  for (int nt = 0; nt < 4; ++nt) acc3[nt] = (f32x4){0.f, 0.f, 0.f, 0.f};
  {
    short8 A0 = wp[12 * 64 + lane];
    short8 A1 = wp[13 * 64 + lane];
#pragma unroll
    for (int nt = 0; nt < 4; ++nt)
      acc3[nt] = __builtin_amdgcn_mfma_f32_16x16x32_bf16(A0, B3[0][nt], acc3[nt], 0, 0, 0);
#pragma unroll
    for (int nt = 0; nt < 4; ++nt)
      acc3[nt] = __builtin_amdgcn_mfma_f32_16x16x32_bf16(A1, B3[1][nt], acc3[nt], 0, 0, 0);
  }

  // ---- store: lane(g<3, r) holds channels 4g..4g+3 of pixel 16nt+r ----
  if (g < 3) {
#pragma unroll
    for (int nt = 0; nt < 4; ++nt) {
      int pix = pixbase + 16 * nt + r;
      *(f32x4*)(out + pix * 12 + 4 * g) = acc3[nt];
    }
  }
}

extern "C" void kernel_launch(void* const* d_in, const int* in_sizes, int n_in,
                              void* d_out, int out_size, void* d_ws, size_t ws_size,
                              hipStream_t stream) {
  const float* rgb = (const float*)d_in[0];
  const float* g0 = (const float*)d_in[1];
  const float* g1 = (const float*)d_in[2];
  const float* g2 = (const float*)d_in[3];
  const float* w1 = (const float*)d_in[4];
  const float* w2 = (const float*)d_in[5];
  const float* w3 = (const float*)d_in[6];
  const int* cam = (const int*)d_in[7];
  float* out = (float*)d_out;

  hipLaunchKernelGGL(prep_kernel, dim3(64), dim3(256), 0, stream,
                     g0, g1, g2, w1, w2, w3, cam, d_ws);
  hipLaunchKernelGGL(msnbat_kernel, dim3(NPIX / 256), dim3(256), 0, stream,
                     rgb, d_ws, out);
}

// Round 6
// 59.788 us; speedup vs baseline: 4.2379x; 1.0660x over previous
//
#include <hip/hip_runtime.h>
#include <hip/hip_bf16.h>

#define H_IMG 720
#define W_IMG 1280
#define NPIX (H_IMG * W_IMG)

typedef __attribute__((ext_vector_type(4))) float f32x4;
typedef __attribute__((ext_vector_type(8))) short short8;
typedef __attribute__((ext_vector_type(4))) short short4v;

// ---- workspace layout (bytes) ----
// wpack: 14 hi-frags * 64 lanes * 16B
#define WPACK_BYTES (14 * 64 * 16)
#define GP0_OFF WPACK_BYTES
#define GP0_N (16 * 16 * 8 * 8)   // [y][x][z][c] f32
#define GP1_OFF (GP0_OFF + GP0_N * 4)
#define GP1_N (12 * 12 * 8 * 8)
#define GP2_OFF (GP1_OFF + GP1_N * 4)
#define GP2_N (8 * 8 * 4 * 8)

#define XSTR 36  // ushorts per staging row: 32 payload + 4 pad

__device__ __forceinline__ uint pkbf(float a, float b) {
  // packed f32x2 -> bf16x2 (v_cvt_pk_bf16_f32), RNE
  float2 t2 = make_float2(a, b);
  __hip_bfloat162 t = __float22bfloat162_rn(t2);
  uint u;
  __builtin_memcpy(&u, &t, 4);
  return u;
}

__device__ __forceinline__ float tanh5(float x) {
  // tanh(x) = 1 - 2/(e^{2x}+1); graceful at +-inf, no clamp needed.
  float e2 = __builtin_amdgcn_exp2f(x * 2.885390081777927f);  // e^{2x} via v_exp_f32
  return fmaf(-2.f, __builtin_amdgcn_rcpf(e2 + 1.f), 1.f);
}

// ================= prep kernel =================
__global__ __launch_bounds__(256) void prep_kernel(
    const float* __restrict__ g0, const float* __restrict__ g1, const float* __restrict__ g2,
    const float* __restrict__ w1, const float* __restrict__ w2, const float* __restrict__ w3,
    const int* __restrict__ cam, void* __restrict__ ws) {
  ushort* wpack = (ushort*)ws;
  float* gp0 = (float*)((char*)ws + GP0_OFF);
  float* gp1 = (float*)((char*)ws + GP1_OFF);
  float* gp2 = (float*)((char*)ws + GP2_OFF);
  const int ci = cam[0];
  const int tid = blockIdx.x * 256 + threadIdx.x;
  const int nth = gridDim.x * 256;

  // grids -> [y][x][z][c] f32, selected view only
  for (int e = tid; e < GP0_N; e += nth) {
    int c = e & 7; int t = e >> 3; int z = t & 7; t >>= 3; int x = t & 15; int y = t >> 4;
    gp0[e] = g0[ci * GP0_N + ((c * 8 + z) * 16 + y) * 16 + x];
  }
  for (int e = tid; e < GP1_N; e += nth) {
    int c = e & 7; int t = e >> 3; int z = t & 7; t >>= 3; int x = t % 12; int y = t / 12;
    gp1[e] = g1[ci * GP1_N + ((c * 8 + z) * 12 + y) * 12 + x];
  }
  for (int e = tid; e < GP2_N; e += nth) {
    int c = e & 7; int t = e >> 3; int z = t & 3; t >>= 2; int x = t & 7; int y = t >> 3;
    gp2[e] = g2[ci * GP2_N + ((c * 4 + z) * 8 + y) * 8 + x];
  }

  // weights -> per-lane A-fragments (A = W^T), hi bf16 only.
  // frag f: 0..3 = L1 (mt), 4..11 = L2 (4+ks*4+mt), 12..13 = L3 (ks).
  for (int fl = tid; fl < 14 * 64; fl += nth) {
    int f = fl >> 6, lane = fl & 63;
    int g = lane >> 4, r = lane & 15;
    ushort* dh = wpack + fl * 8;
#pragma unroll
    for (int j = 0; j < 8; ++j) {
      float v = 0.f;
      if (f < 4) {
        int k = 8 * g + j, n = r + 16 * f;
        if (k < 24) v = w1[k * 64 + n];
      } else if (f < 12) {
        int q = f - 4, ks = q >> 2, mt = q & 3;
        v = w2[(8 * g + j + 32 * ks) * 64 + (r + 16 * mt)];
      } else {
        int ks = f - 12;
        if (r < 12) v = w3[(8 * g + j + 32 * ks) * 12 + r];
      }
      __hip_bfloat16 bh = __float2bfloat16(v);
      dh[j] = *(ushort*)&bh;
    }
  }
}

// ================= slicing =================
template <int WG, int HG, int LG>
__device__ __forceinline__ void slice_pack(const float* __restrict__ gp,
                                           int row, int col, float gray,
                                           float* __restrict__ out8) {
  float x = (float)col * ((float)(WG - 1) / (float)(W_IMG - 1));
  float y = (float)row * ((float)(HG - 1) / (float)(H_IMG - 1));
  float z = gray * (float)(LG - 1);
  int x0 = (int)x, y0 = (int)y, z0 = (int)z;
  int x1 = min(x0 + 1, WG - 1), y1 = min(y0 + 1, HG - 1), z1 = min(z0 + 1, LG - 1);
  float wx = x - (float)x0, wy = y - (float)y0, wz = z - (float)z0;

  const float* p00 = gp + ((y0 * WG + x0) * LG) * 8;
  const float* p01 = gp + ((y0 * WG + x1) * LG) * 8;
  const float* p10 = gp + ((y1 * WG + x0) * LG) * 8;
  const float* p11 = gp + ((y1 * WG + x1) * LG) * 8;

  f32x4 s00a = *(const f32x4*)(p00 + z0 * 8), s00b = *(const f32x4*)(p00 + z0 * 8 + 4);
  f32x4 s01a = *(const f32x4*)(p01 + z0 * 8), s01b = *(const f32x4*)(p01 + z0 * 8 + 4);
  f32x4 s10a = *(const f32x4*)(p10 + z0 * 8), s10b = *(const f32x4*)(p10 + z0 * 8 + 4);
  f32x4 s11a = *(const f32x4*)(p11 + z0 * 8), s11b = *(const f32x4*)(p11 + z0 * 8 + 4);
  f32x4 t00a = *(const f32x4*)(p00 + z1 * 8), t00b = *(const f32x4*)(p00 + z1 * 8 + 4);
  f32x4 t01a = *(const f32x4*)(p01 + z1 * 8), t01b = *(const f32x4*)(p01 + z1 * 8 + 4);
  f32x4 t10a = *(const f32x4*)(p10 + z1 * 8), t10b = *(const f32x4*)(p10 + z1 * 8 + 4);
  f32x4 t11a = *(const f32x4*)(p11 + z1 * 8), t11b = *(const f32x4*)(p11 + z1 * 8 + 4);

#pragma unroll
  for (int c = 0; c < 8; ++c) {
    float c00 = (c < 4) ? s00a[c & 3] : s00b[c & 3];
    float c01 = (c < 4) ? s01a[c & 3] : s01b[c & 3];
    float c10 = (c < 4) ? s10a[c & 3] : s10b[c & 3];
    float c11 = (c < 4) ? s11a[c & 3] : s11b[c & 3];
    float d00 = (c < 4) ? t00a[c & 3] : t00b[c & 3];
    float d01 = (c < 4) ? t01a[c & 3] : t01b[c & 3];
    float d10 = (c < 4) ? t10a[c & 3] : t10b[c & 3];
    float d11 = (c < 4) ? t11a[c & 3] : t11b[c & 3];
    float h0 = fmaf(wx, c01 - c00, c00);
    float h1 = fmaf(wx, c11 - c10, c10);
    float v0 = fmaf(wy, h1 - h0, h0);
    float g0v = fmaf(wx, d01 - d00, d00);
    float g1v = fmaf(wx, d11 - d10, d10);
    float v1 = fmaf(wy, g1v - g0v, g0v);
    out8[c] = fmaf(wz, v1 - v0, v0);
  }
}

// ================= main kernel =================
// One reused 64x36-ushort staging region per wave: X -> H1a -> H1b -> H2a -> H2b.
// All DS traffic is wave-private and in-order; no barriers anywhere.
// launch_bounds(256,4): VGPR cap 128 -- rounds 4/5 showed live set ~95-116;
// (256,5)'s 102 cap forced B-frag scratch spills (+53MB WRITE_SIZE).
__global__ __launch_bounds__(256, 4) void msnbat_kernel(
    const float* __restrict__ rgb, const void* __restrict__ ws, float* __restrict__ out) {
  __shared__ ushort LDS[4][64 * XSTR];  // 18432 B/block

  const short8* wp = (const short8*)ws;  // frag f, lane l -> wp[f*64+l]
  const float* gp0 = (const float*)((const char*)ws + GP0_OFF);
  const float* gp1 = (const float*)((const char*)ws + GP1_OFF);
  const float* gp2 = (const float*)((const char*)ws + GP2_OFF);

  const int wave = threadIdx.x >> 6, lane = threadIdx.x & 63;
  const int g = lane >> 4, r = lane & 15;
  ushort* W = LDS[wave];
  uint* Wu = (uint*)W;
  const int pixbase = blockIdx.x * 256 + wave * 64;
  const int p = pixbase + lane;
  const int row = p / W_IMG;
  const int col = p - row * W_IMG;

  const float rr = rgb[p * 3 + 0], gg = rgb[p * 3 + 1], bb = rgb[p * 3 + 2];
  const float gray = fminf(fmaxf(rr * 0.299f + gg * 0.587f + bb * 0.114f, 0.f), 1.f);

  // ---- slice 24 features (lane = its own pixel) ----
  float f[24];
  slice_pack<16, 16, 8>(gp0, row, col, gray, f);
  slice_pack<12, 12, 8>(gp1, row, col, gray, f + 8);
  slice_pack<8, 8, 4>(gp2, row, col, gray, f + 16);

  // ---- stage X: row = pixel(lane), cols 0..23 bf16 feats, 24..31 zero ----
  {
    const int ub = lane * 18;  // uint base of this row
#pragma unroll
    for (int i = 0; i < 6; ++i) {
      uint2 v = make_uint2(pkbf(f[4 * i + 0], f[4 * i + 1]), pkbf(f[4 * i + 2], f[4 * i + 3]));
      *(uint2*)&Wu[ub + 2 * i] = v;
    }
    uint2 z2 = make_uint2(0u, 0u);
    *(uint2*)&Wu[ub + 12] = z2;
    *(uint2*)&Wu[ub + 14] = z2;
  }

  // ---- B1 frags: lane(g,r) reads X[pixel r+16nt][feat 8g+j] ----
  short8 B1[4];
#pragma unroll
  for (int nt = 0; nt < 4; ++nt) {
    short4v lo = *(short4v*)&W[(r + 16 * nt) * XSTR + 8 * g];
    short4v hi = *(short4v*)&W[(r + 16 * nt) * XSTR + 8 * g + 4];
    B1[nt] = __builtin_shufflevector(lo, hi, 0, 1, 2, 3, 4, 5, 6, 7);
  }

  // ---- L1 (24->64) in mt-halves; stage tanh(H1) halves; build B2 frags ----
  short8 B2[2][4];
#pragma unroll
  for (int half = 0; half < 2; ++half) {
#pragma unroll
    for (int mtl = 0; mtl < 2; ++mtl) {
      const int mt = 2 * half + mtl;
      short8 A = wp[mt * 64 + lane];
      f32x4 a[4];
#pragma unroll
      for (int nt = 0; nt < 4; ++nt) a[nt] = (f32x4){0.f, 0.f, 0.f, 0.f};
#pragma unroll
      for (int nt = 0; nt < 4; ++nt)
        a[nt] = __builtin_amdgcn_mfma_f32_16x16x32_bf16(A, B1[nt], a[nt], 0, 0, 0);
#pragma unroll
      for (int nt = 0; nt < 4; ++nt) {
        uint2 v = make_uint2(pkbf(tanh5(a[nt][0]), tanh5(a[nt][1])),
                             pkbf(tanh5(a[nt][2]), tanh5(a[nt][3])));
        *(uint2*)&Wu[(16 * nt + r) * 18 + 8 * mtl + 2 * g] = v;
      }
    }
#pragma unroll
    for (int nt = 0; nt < 4; ++nt) {
      short4v lo = *(short4v*)&W[(16 * nt + r) * XSTR + 8 * g];
      short4v hi = *(short4v*)&W[(16 * nt + r) * XSTR + 8 * g + 4];
      B2[half][nt] = __builtin_shufflevector(lo, hi, 0, 1, 2, 3, 4, 5, 6, 7);
    }
  }

  // ---- L2 (64->64) in mt-halves; stage tanh(H2) halves; build B3 frags ----
  short8 B3[2][4];
#pragma unroll
  for (int half = 0; half < 2; ++half) {
#pragma unroll
    for (int mtl = 0; mtl < 2; ++mtl) {
      const int mt = 2 * half + mtl;
      short8 A0 = wp[(4 + mt) * 64 + lane];  // ks=0
      short8 A1 = wp[(8 + mt) * 64 + lane];  // ks=1
      f32x4 a[4];
#pragma unroll
      for (int nt = 0; nt < 4; ++nt) a[nt] = (f32x4){0.f, 0.f, 0.f, 0.f};
#pragma unroll
      for (int nt = 0; nt < 4; ++nt)
        a[nt] = __builtin_amdgcn_mfma_f32_16x16x32_bf16(A0, B2[0][nt], a[nt], 0, 0, 0);
#pragma unroll
      for (int nt = 0; nt < 4; ++nt)
        a[nt] = __builtin_amdgcn_mfma_f32_16x16x32_bf16(A1, B2[1][nt], a[nt], 0, 0, 0);
#pragma unroll
      for (int nt = 0; nt < 4; ++nt) {
        uint2 v = make_uint2(pkbf(tanh5(a[nt][0]), tanh5(a[nt][1])),
                             pkbf(tanh5(a[nt][2]), tanh5(a[nt][3])));
        *(uint2*)&Wu[(16 * nt + r) * 18 + 8 * mtl + 2 * g] = v;
      }
    }
#pragma unroll
    for (int nt = 0; nt < 4; ++nt) {
      short4v lo = *(short4v*)&W[(16 * nt + r) * XSTR + 8 * g];
      short4v hi = *(short4v*)&W[(16 * nt + r) * XSTR + 8 * g + 4];
      B3[half][nt] = __builtin_shufflevector(lo, hi, 0, 1, 2, 3, 4, 5, 6, 7);
    }
  }

  // ---- L3 (64->12): M=16 (12 valid), K=64 ----
  f32x4 acc3[4];
#pragma unroll
  for (int nt = 0; nt < 4; ++nt) acc3[nt] = (f32x4){0.f, 0.f, 0.f, 0.f};
  {
    short8 A0 = wp[12 * 64 + lane];
    short8 A1 = wp[13 * 64 + lane];
#pragma unroll
    for (int nt = 0; nt < 4; ++nt)
      acc3[nt] = __builtin_amdgcn_mfma_f32_16x16x32_bf16(A0, B3[0][nt], acc3[nt], 0, 0, 0);
#pragma unroll
    for (int nt = 0; nt < 4; ++nt)
      acc3[nt] = __builtin_amdgcn_mfma_f32_16x16x32_bf16(A1, B3[1][nt], acc3[nt], 0, 0, 0);
  }

  // ---- store: lane(g<3, r) holds channels 4g..4g+3 of pixel 16nt+r ----
  if (g < 3) {
#pragma unroll
    for (int nt = 0; nt < 4; ++nt) {
      int pix = pixbase + 16 * nt + r;
      *(f32x4*)(out + pix * 12 + 4 * g) = acc3[nt];
    }
  }
}

extern "C" void kernel_launch(void* const* d_in, const int* in_sizes, int n_in,
                              void* d_out, int out_size, void* d_ws, size_t ws_size,
                              hipStream_t stream) {
  const float* rgb = (const float*)d_in[0];
  const float* g0 = (const float*)d_in[1];
  const float* g1 = (const float*)d_in[2];
  const float* g2 = (const float*)d_in[3];
  const float* w1 = (const float*)d_in[4];
  const float* w2 = (const float*)d_in[5];
  const float* w3 = (const float*)d_in[6];
  const int* cam = (const int*)d_in[7];
  float* out = (float*)d_out;

  hipLaunchKernelGGL(prep_kernel, dim3(64), dim3(256), 0, stream,
                     g0, g1, g2, w1, w2, w3, cam, d_ws);
  hipLaunchKernelGGL(msnbat_kernel, dim3(NPIX / 256), dim3(256), 0, stream,
                     rgb, d_ws, out);
}